// Round 1
// baseline (794.646 us; speedup 1.0000x reference)
//
#include <hip/hip_runtime.h>
#include <hip/hip_bf16.h>
#include <stdint.h>

// BinaryLinearLayer: out = sign(x) @ sign(w), x:[N,4096] f32, w:[4096,4096] f32.
// Exact integer path: pack sign bits (bit=1 iff v<0, matching v>=0 -> +1),
// dot(a,b) = K - 2*popcount(a^b).

#define DIN   4096
#define DOUT  4096
#define KW    (DIN / 32)   // 128 k-words
#define BM    128
#define BN    128
#define BKW   32           // k-words per LDS tile (1024 k-bits)
#define TM    8
#define TN    8

// ---- pack x: one wave per row-chunk, ballot builds 64 k-bits at a time ----
__global__ __launch_bounds__(256) void pack_x_kernel(const float* __restrict__ x,
                                                     uint32_t* __restrict__ xp) {
    const int wave = threadIdx.x >> 6;   // 0..3
    const int lane = threadIdx.x & 63;
    const int n = blockIdx.x * 4 + wave;
    const float* row = x + (size_t)n * DIN;
    unsigned long long* dst = (unsigned long long*)xp + (size_t)n * (KW / 2);
    #pragma unroll 4
    for (int c = 0; c < DIN / 64; c++) {
        float v = row[c * 64 + lane];
        unsigned long long m = __ballot(v < 0.0f);   // bit i = lane i = k offset i
        if (lane == 0) dst[c] = m;
    }
}

// ---- pack w: wp layout [kc][out] (kc-major) so GEMM B-tile loads coalesce ----
__global__ __launch_bounds__(256) void pack_w_kernel(const float* __restrict__ w,
                                                     uint32_t* __restrict__ wp) {
    const int out = blockIdx.x * 256 + threadIdx.x;
    const int kc  = blockIdx.y;                      // 0..KW-1
    const float* base = w + (size_t)(kc * 32) * DOUT + out;
    uint32_t word = 0;
    #pragma unroll
    for (int j = 0; j < 32; j++) {
        word |= (base[(size_t)j * DOUT] < 0.0f ? 1u : 0u) << j;
    }
    wp[(size_t)kc * DOUT + out] = word;
}

// ---- bit-GEMM: C[n][o] = DIN - 2 * sum_kc popc(xp[n][kc] ^ wp[kc][o]) ----
__global__ __launch_bounds__(256) void bgemm_kernel(const uint32_t* __restrict__ xp,
                                                    const uint32_t* __restrict__ wp,
                                                    float* __restrict__ out) {
    __shared__ uint32_t xs[BKW][BM + 1];   // [kword][row], +1 pad breaks bank stride
    __shared__ uint32_t ws[BKW][BN + 1];   // [kword][col]

    const int t  = threadIdx.x;
    const int bm = blockIdx.y * BM;
    const int bn = blockIdx.x * BN;
    const int ty = t >> 4;                 // 0..15
    const int tx = t & 15;                 // 0..15
    const int rowBase = ty * TM;
    const int colBase = tx * TN;

    int acc[TM][TN];
    #pragma unroll
    for (int i = 0; i < TM; i++)
        #pragma unroll
        for (int j = 0; j < TN; j++) acc[i][j] = 0;

    const int xcol = t & 31;               // word within tile
    const int xr0  = t >> 5;               // 0..7
    const int wcol = t & 127;
    const int wk0  = t >> 7;               // 0..1

    for (int kw0 = 0; kw0 < KW; kw0 += BKW) {
        // A-tile: 128 rows x 32 words, stored transposed [word][row]
        #pragma unroll
        for (int i = 0; i < 16; i++) {
            int row = xr0 + i * 8;
            xs[xcol][row] = xp[(size_t)(bm + row) * KW + kw0 + xcol];
        }
        // B-tile: 32 kwords x 128 cols
        #pragma unroll
        for (int i = 0; i < 16; i++) {
            int kc = wk0 + i * 2;
            ws[kc][wcol] = wp[(size_t)(kw0 + kc) * DOUT + bn + wcol];
        }
        __syncthreads();

        #pragma unroll
        for (int kc = 0; kc < BKW; kc++) {
            uint32_t a[TM], b[TN];
            #pragma unroll
            for (int i = 0; i < TM; i++) a[i] = xs[kc][rowBase + i];
            #pragma unroll
            for (int j = 0; j < TN; j++) b[j] = ws[kc][colBase + j];
            #pragma unroll
            for (int i = 0; i < TM; i++)
                #pragma unroll
                for (int j = 0; j < TN; j++)
                    acc[i][j] += __popc(a[i] ^ b[j]);
        }
        __syncthreads();
    }

    // epilogue: C = K - 2*popc_sum, float4 stores
    #pragma unroll
    for (int i = 0; i < TM; i++) {
        float* o = out + (size_t)(bm + rowBase + i) * DOUT + bn + colBase;
        float vals[TN];
        #pragma unroll
        for (int j = 0; j < TN; j++) vals[j] = (float)(DIN - 2 * acc[i][j]);
        ((float4*)o)[0] = make_float4(vals[0], vals[1], vals[2], vals[3]);
        ((float4*)o)[1] = make_float4(vals[4], vals[5], vals[6], vals[7]);
    }
}

extern "C" void kernel_launch(void* const* d_in, const int* in_sizes, int n_in,
                              void* d_out, int out_size, void* d_ws, size_t ws_size,
                              hipStream_t stream) {
    const float* x = (const float*)d_in[0];
    const float* w = (const float*)d_in[1];
    float* out = (float*)d_out;
    const int N = in_sizes[0] / DIN;       // 8192

    uint32_t* xp = (uint32_t*)d_ws;                                  // N * 128 words = 4 MB
    uint32_t* wp = (uint32_t*)((char*)d_ws + (size_t)N * KW * 4);    // 128 * 4096 words = 2 MB

    pack_x_kernel<<<N / 4, 256, 0, stream>>>(x, xp);
    pack_w_kernel<<<dim3(DOUT / 256, KW), 256, 0, stream>>>(w, wp);
    bgemm_kernel<<<dim3(DOUT / BN, N / BM), 256, 0, stream>>>(xp, wp, out);
}